// Round 3
// baseline (1953.216 us; speedup 1.0000x reference)
//
#include <hip/hip_runtime.h>

#define EE 131072
#define NNODE 16384
#define FEAT 120
#define NS 512
#define NB 256
#define KCAT 1344

typedef unsigned short u16;
typedef __bf16 bf16x8 __attribute__((ext_vector_type(8)));
typedef float f32x4 __attribute__((ext_vector_type(4)));
typedef unsigned short ushort8 __attribute__((ext_vector_type(8)));

__device__ __forceinline__ float b2f(u16 u) {
  union { unsigned int i; float f; } x; x.i = ((unsigned int)u) << 16; return x.f;
}
__device__ __forceinline__ u16 f2b(float f) {
  union { float f; unsigned int i; } x; x.f = f;
  unsigned int lsb = (x.i >> 16) & 1u;
  x.i += 0x7fffu + lsb;
  return (u16)(x.i >> 16);
}
__device__ __forceinline__ float rdany(const void* p, long i, int f32) {
  return f32 ? ((const float*)p)[i] : b2f(((const u16*)p)[i]);
}

__device__ __forceinline__ void gload16(const u16* g, u16* l) {
  __builtin_amdgcn_global_load_lds(
      (__attribute__((address_space(1))) void*)(u16*)g,
      (__attribute__((address_space(3))) void*)l, 16, 0, 0);
}

// ---------------- dtype detection ----------------
// bf16 normal data: exponent field < 0x48 (|x| < 256) for every element.
// fp32 data read as u16: even halfwords are mantissa bits ~ uniform -> ~72% >= 0x48.
__global__ void detect_k(const u16* __restrict__ nodes, int* __restrict__ flag) {
  __shared__ int cnt;
  if (threadIdx.x == 0) cnt = 0;
  __syncthreads();
  u16 v = nodes[threadIdx.x];  // 256 threads, 512 bytes - safe for either dtype
  int e = (v >> 7) & 0xFF;
  if (e >= 0x48) atomicAdd(&cnt, 1);
  __syncthreads();
  if (threadIdx.x == 0) *flag = (cnt >= 16) ? 1 : 0;
}

__global__ __launch_bounds__(256) void convert_k(const void* __restrict__ src,
                                                 u16* __restrict__ dst, long n,
                                                 const int* __restrict__ flag) {
  long i = (long)blockIdx.x * 256 + threadIdx.x;
  if (i >= n) return;
  if (*flag)
    dst[i] = f2b(((const float*)src)[i]);
  else
    dst[i] = ((const u16*)src)[i];
}

// ---------------- weight prep ----------------
__global__ __launch_bounds__(256) void transpose_k(const u16* __restrict__ in,
                                                   u16* __restrict__ out, int R, int C) {
  __shared__ u16 tile[32][33];
  int c0 = blockIdx.x * 32, r0 = blockIdx.y * 32;
  int tx = threadIdx.x & 31, ty = threadIdx.x >> 5;  // 32x8
  for (int i = 0; i < 32; i += 8) {
    int r = r0 + ty + i, c = c0 + tx;
    if (r < R && c < C) tile[ty + i][tx] = in[(long)r * C + c];
  }
  __syncthreads();
  for (int i = 0; i < 32; i += 8) {
    int r = r0 + tx, c = c0 + ty + i;
    if (r < R && c < C) out[(long)c * R + r] = tile[tx][ty + i];
  }
}

__global__ __launch_bounds__(256) void build_wcat(const u16* __restrict__ W0,
                                                  const u16* __restrict__ W1,
                                                  const u16* __restrict__ W2,
                                                  u16* __restrict__ wcT) {
  int idx = blockIdx.x * 256 + threadIdx.x;  // over 512*1344
  if (idx >= NS * KCAT) return;
  int w = idx / KCAT, k = idx - w * KCAT;
  const float fan = 36.66060556f;  // sqrt(1344)
  float val;
  if (k < 1024) {
    int u = k >> 5, v = k & 31;
    val = 0.5f * (b2f(W0[(u * 32 + v) * NS + w]) + b2f(W0[(v * 32 + u) * NS + w])) / fan;
  } else if (k < 1280) {
    int j = k - 1024;
    int u = j >> 4, v = j & 15;
    val = 0.5f * (b2f(W1[(u * 16 + v) * NS + w]) + b2f(W1[(v * 16 + u) * NS + w])) /
          (fan * 1.7320508076f);
  } else {
    int j = k - 1280;
    int u = j >> 3, v = j & 7;
    val = 0.5f * (b2f(W2[(u * 8 + v) * NS + w]) + b2f(W2[(v * 8 + u) * NS + w])) /
          (fan * 2.2360679775f);
  }
  wcT[idx] = f2b(val);
}

// ---------------- per-edge geometry + embedding + outer products ----------------
__global__ __launch_bounds__(256) void edge_prep(
    const u16* __restrict__ nodes, const void* __restrict__ pos, const void* __restrict__ cell,
    const void* __restrict__ shift, const int* __restrict__ eidx, const int* __restrict__ batch,
    u16* __restrict__ emb, u16* __restrict__ ocat, int e0, const int* __restrict__ flag) {
  const int wave = threadIdx.x >> 6, lane = threadIdx.x & 63;
  const int el = blockIdx.x * 4 + wave;
  const int e = e0 + el;
  const int f32 = *flag;
  __shared__ u16 sxs[4][FEAT], sxd[4][FEAT];
  const int src = eidx[e], dst = eidx[EE + e];
  for (int i = lane; i < FEAT; i += 64) {
    sxs[wave][i] = nodes[(long)src * FEAT + i];
    sxd[wave][i] = nodes[(long)dst * FEAT + i];
  }
  __syncthreads();
  const int b = batch[src];
  float s0 = rdany(shift, (long)e * 3, f32), s1 = rdany(shift, (long)e * 3 + 1, f32),
        s2 = rdany(shift, (long)e * 3 + 2, f32);
  float d2 = 0.f;
#pragma unroll
  for (int j = 0; j < 3; j++) {
    float tv = s0 * rdany(cell, b * 9 + j, f32) + s1 * rdany(cell, b * 9 + 3 + j, f32) +
               s2 * rdany(cell, b * 9 + 6 + j, f32);
    float rv = rdany(pos, dst * 3 + j, f32) - rdany(pos, src * 3 + j, f32) + tv;
    d2 += rv * rv;
  }
  float dist = sqrtf(d2);
  float r = 1.0f / (dist + 1e-6f);
  const float c0 = 0.5345224838f;   // sqrt(2/7)
  const float pi7 = 0.44879895051f; // pi/7
#pragma unroll
  for (int j = 0; j < 4; j++) {
    int n = lane + 64 * j;
    float val = c0 * sinf((float)(n + 1) * pi7 * r) / r;
    emb[(long)el * NB + n] = f2b(val);
  }
  const u16* xs = sxs[wave];
  const u16* xd = sxd[wave];
  u16* orow = ocat + (long)el * KCAT;
#pragma unroll
  for (int j = 0; j < 16; j++) {
    int k = lane + 64 * j;
    int u = k >> 5, v = k & 31;
    orow[k] = f2b(b2f(xs[u]) * b2f(xd[v]));
  }
#pragma unroll
  for (int j = 0; j < 4; j++) {
    int k = lane + 64 * j;
    int u = k >> 4, v = k & 15;
    float s = 0.f;
#pragma unroll
    for (int i = 0; i < 3; i++) s += b2f(xs[32 + u * 3 + i]) * b2f(xd[32 + v * 3 + i]);
    orow[1024 + k] = f2b(s);
  }
  {
    int u = lane >> 3, v = lane & 7;
    float s = 0.f;
#pragma unroll
    for (int i = 0; i < 5; i++) s += b2f(xs[80 + u * 5 + i]) * b2f(xd[80 + v * 5 + i]);
    orow[1280 + lane] = f2b(s);
  }
}

// ---------------- tiled MFMA GEMM: C(MxN) = act(A(MxK) @ BT(NxK)^T + bias) ----------------
template <int ACT, int OF32>
__global__ __launch_bounds__(256) void gemm_bt(const u16* __restrict__ A,
                                               const u16* __restrict__ BT,
                                               const u16* __restrict__ bias,
                                               void* __restrict__ Cv, int N, int K) {
  __shared__ __align__(16) u16 lA[128 * 32];
  __shared__ __align__(16) u16 lB[128 * 32];
  const int tid = threadIdx.x;
  const int wave = tid >> 6, lane = tid & 63;
  const int quad = lane >> 4, l16 = lane & 15;
  const long m0 = (long)blockIdx.y * 128;
  const int n0 = blockIdx.x * 128;
  const int wm = (wave >> 1) * 64, wn = (wave & 1) * 64;

  f32x4 acc[4][4];
#pragma unroll
  for (int i = 0; i < 4; i++)
#pragma unroll
    for (int j = 0; j < 4; j++) acc[i][j] = (f32x4){0.f, 0.f, 0.f, 0.f};

  const int r0 = tid >> 2, sg = (tid & 3) * 8;
  const u16* Ag0 = A + (m0 + r0) * K + sg;
  const u16* Ag1 = A + (m0 + r0 + 64) * K + sg;
  const u16* Bg0 = BT + (long)(n0 + r0) * K + sg;
  const u16* Bg1 = BT + (long)(n0 + r0 + 64) * K + sg;

  for (int k0 = 0; k0 < K; k0 += 32) {
    gload16(Ag0 + k0, &lA[tid * 8]);
    gload16(Ag1 + k0, &lA[(tid + 256) * 8]);
    gload16(Bg0 + k0, &lB[tid * 8]);
    gload16(Bg1 + k0, &lB[(tid + 256) * 8]);
    __syncthreads();
    bf16x8 af[4], bfr[4];
#pragma unroll
    for (int t = 0; t < 4; t++) {
      af[t] = *(const bf16x8*)&lA[(wm + t * 16 + l16) * 32 + quad * 8];
      bfr[t] = *(const bf16x8*)&lB[(wn + t * 16 + l16) * 32 + quad * 8];
    }
#pragma unroll
    for (int mt = 0; mt < 4; mt++)
#pragma unroll
      for (int nt = 0; nt < 4; nt++)
        acc[mt][nt] =
            __builtin_amdgcn_mfma_f32_16x16x32_bf16(af[mt], bfr[nt], acc[mt][nt], 0, 0, 0);
    __syncthreads();
  }

  float* Cf = (float*)Cv;
  u16* Cb = (u16*)Cv;
#pragma unroll
  for (int mt = 0; mt < 4; mt++) {
#pragma unroll
    for (int nt = 0; nt < 4; nt++) {
      const int col = n0 + wn + nt * 16 + l16;
      float bv = bias ? b2f(bias[col]) : 0.0f;
#pragma unroll
      for (int i = 0; i < 4; i++) {
        long row = m0 + wm + mt * 16 + quad * 4 + i;
        float v = acc[mt][nt][i] + bv;
        if (ACT) v = v / (1.0f + __expf(-v));
        if (OF32)
          Cf[row * N + col] = v;
        else
          Cb[row * N + col] = f2b(v);
      }
    }
  }
}

// ---------------- LayerNorm * distfilter (in-place over distfilter) ----------------
__global__ __launch_bounds__(256) void ln_mul_k(const float* __restrict__ mixed,
                                                const u16* __restrict__ g,
                                                const u16* __restrict__ bvec,
                                                u16* __restrict__ dfreg) {
  const int wave = threadIdx.x >> 6, lane = threadIdx.x & 63;
  const long e = (long)blockIdx.x * 4 + wave;
  const float* row = mixed + e * NS;
  float x[8];
  f32x4 v0 = *(const f32x4*)&row[lane * 8];
  f32x4 v1 = *(const f32x4*)&row[lane * 8 + 4];
#pragma unroll
  for (int j = 0; j < 4; j++) { x[j] = v0[j]; x[4 + j] = v1[j]; }
  float s = 0.f, sq = 0.f;
#pragma unroll
  for (int j = 0; j < 8; j++) { s += x[j]; sq += x[j] * x[j]; }
  for (int o = 32; o; o >>= 1) { s += __shfl_xor(s, o); sq += __shfl_xor(sq, o); }
  float mu = s * (1.0f / 512.0f);
  float var = sq * (1.0f / 512.0f) - mu * mu;
  float rstd = rsqrtf(var + 1e-5f);
  u16* drow = dfreg + e * NS;
  ushort8 dv = *(const ushort8*)&drow[lane * 8];
  ushort8 ov;
#pragma unroll
  for (int j = 0; j < 8; j++) {
    int c = lane * 8 + j;
    float val = (x[j] - mu) * rstd * b2f(g[c]) + b2f(bvec[c]);
    ov[j] = f2b(val * b2f(dv[j]));
  }
  *(ushort8*)&drow[lane * 8] = ov;
}

// ---------------- final GEMV head (dtype-adaptive output) ----------------
__global__ __launch_bounds__(256) void gemv_out(const u16* __restrict__ h3,
                                                const u16* __restrict__ w,
                                                const u16* __restrict__ b,
                                                void* __restrict__ out, int e0,
                                                const int* __restrict__ flag) {
  const int wave = threadIdx.x >> 6, lane = threadIdx.x & 63;
  const long e = (long)blockIdx.x * 4 + wave;
  const u16* row = h3 + e * 1024;
  float s = 0.f;
#pragma unroll
  for (int c = 0; c < 2; c++) {
    ushort8 hv = *(const ushort8*)&row[lane * 16 + c * 8];
    ushort8 wv = *(const ushort8*)&w[lane * 16 + c * 8];
#pragma unroll
    for (int j = 0; j < 8; j++) s += b2f(hv[j]) * b2f(wv[j]);
  }
  for (int o = 32; o; o >>= 1) s += __shfl_xor(s, o);
  if (lane == 0) {
    float v = s + b2f(b[0]);
    if (*flag)
      ((float*)out)[e0 + e] = v;
    else
      ((u16*)out)[e0 + e] = f2b(v);
  }
}

extern "C" void kernel_launch(void* const* d_in, const int* in_sizes, int n_in, void* d_out,
                              int out_size, void* d_ws, size_t ws_size, hipStream_t stream) {
  const int* eidx = (const int*)d_in[19];
  const int* batch = (const int*)d_in[20];

  char* ws = (char*)d_ws;
  size_t off = 0;
  auto alloc = [&](size_t bytes) {
    char* p = ws + off;
    off += (bytes + 255) & ~(size_t)255;
    return p;
  };

  int* flag = (int*)alloc(256);

  // detect input dtype (device-side, deterministic every call)
  detect_k<<<1, 256, 0, stream>>>((const u16*)d_in[0], flag);

  // normalize all 19 float tensors to bf16 copies
  u16* cv[19];
  for (int i = 0; i < 19; i++) {
    long n = in_sizes[i];
    cv[i] = (u16*)alloc((size_t)n * 2);
    convert_k<<<(int)((n + 255) / 256), 256, 0, stream>>>(d_in[i], cv[i], n, flag);
  }
  const u16* nodes = cv[0];
  const u16* W0 = cv[4];
  const u16* W1 = cv[5];
  const u16* W2 = cv[6];
  const u16* ln_g = cv[7];
  const u16* ln_b = cv[8];
  const u16* df_w1 = cv[9];
  const u16* df_b1 = cv[10];
  const u16* df_w2 = cv[11];
  const u16* df_b2 = cv[12];
  const u16* mi_w1 = cv[13];
  const u16* mi_b1 = cv[14];
  const u16* mi_w2 = cv[15];
  const u16* mi_b2 = cv[16];
  const u16* mo_w = cv[17];
  const u16* mo_b = cv[18];

  // fixed weight buffers
  u16* w1T = (u16*)alloc(1024 * 256 * 2);
  u16* w2T = (u16*)alloc(512 * 1024 * 2);
  u16* m1T = (u16*)alloc(1024 * 512 * 2);
  u16* m2T = (u16*)alloc((size_t)1024 * 1024 * 2);
  u16* wcT = (u16*)alloc((size_t)NS * KCAT * 2);

  // pick chunk count so per-chunk buffers fit in remaining workspace.
  // per-edge bytes: ocat 2688 + emb 512 + h1/mixed 2048 + dfb 1024 = 6272
  int nchunk = 1;
  while (nchunk < 64) {
    size_t CHs = (size_t)(EE / nchunk);
    size_t need = off + CHs * 6272 + 8192;
    if (need <= ws_size) break;
    nchunk <<= 1;
  }
  const int CH = EE / nchunk;

  u16* ocat = (u16*)alloc((size_t)CH * KCAT * 2);  // reused as h2
  u16* emb = (u16*)alloc((size_t)CH * NB * 2);
  u16* h1 = (u16*)alloc((size_t)CH * 1024 * 2);  // reused as mixed(f32), h3
  u16* dfb = (u16*)alloc((size_t)CH * NS * 2);   // distfilter, then reg in-place
  u16* h2 = ocat;
  float* mixed = (float*)h1;
  u16* h3 = h1;

  // weight prep (once)
  transpose_k<<<dim3(1024 / 32, 256 / 32), 256, 0, stream>>>(df_w1, w1T, 256, 1024);
  transpose_k<<<dim3(512 / 32, 1024 / 32), 256, 0, stream>>>(df_w2, w2T, 1024, 512);
  transpose_k<<<dim3(1024 / 32, 512 / 32), 256, 0, stream>>>(mi_w1, m1T, 512, 1024);
  transpose_k<<<dim3(1024 / 32, 1024 / 32), 256, 0, stream>>>(mi_w2, m2T, 1024, 1024);
  build_wcat<<<(NS * KCAT + 255) / 256, 256, 0, stream>>>(W0, W1, W2, wcT);

  for (int c = 0; c < nchunk; c++) {
    const int eb = c * CH;
    edge_prep<<<CH / 4, 256, 0, stream>>>(nodes, d_in[1], d_in[2], d_in[3], eidx, batch, emb,
                                          ocat, eb, flag);

    // distance-filter MLP
    gemm_bt<1, 0><<<dim3(8, CH / 128), 256, 0, stream>>>(emb, w1T, df_b1, h1, 1024, 256);
    gemm_bt<0, 0><<<dim3(4, CH / 128), 256, 0, stream>>>(h1, w2T, df_b2, dfb, 512, 1024);

    // tensor-product mixing -> mixed (fp32)
    gemm_bt<0, 1><<<dim3(4, CH / 128), 256, 0, stream>>>(ocat, wcT, nullptr, mixed, 512, 1344);

    // LayerNorm * distfilter -> reg (in-place over dfb)
    ln_mul_k<<<CH / 4, 256, 0, stream>>>(mixed, ln_g, ln_b, dfb);

    // output MLP
    gemm_bt<1, 0><<<dim3(8, CH / 128), 256, 0, stream>>>(dfb, m1T, mi_b1, h2, 1024, 512);
    gemm_bt<1, 0><<<dim3(8, CH / 128), 256, 0, stream>>>(h2, m2T, mi_b2, h3, 1024, 1024);

    // head
    gemv_out<<<CH / 4, 256, 0, stream>>>(h3, mo_w, mo_b, d_out, eb, flag);
  }
}

// Round 4
// 1761.494 us; speedup vs baseline: 1.1088x; 1.1088x over previous
//
#include <hip/hip_runtime.h>

#define EE 131072
#define NNODE 16384
#define FEAT 120
#define NS 512
#define NB 256
#define KCAT 1344

typedef unsigned short u16;
typedef __bf16 bf16x8 __attribute__((ext_vector_type(8)));
typedef float f32x4 __attribute__((ext_vector_type(4)));
typedef unsigned short ushort8 __attribute__((ext_vector_type(8)));

__device__ __forceinline__ float b2f(u16 u) {
  union { unsigned int i; float f; } x; x.i = ((unsigned int)u) << 16; return x.f;
}
__device__ __forceinline__ u16 f2b(float f) {
  union { float f; unsigned int i; } x; x.f = f;
  unsigned int lsb = (x.i >> 16) & 1u;
  x.i += 0x7fffu + lsb;
  return (u16)(x.i >> 16);
}
__device__ __forceinline__ float rdany(const void* p, long i, int f32) {
  return f32 ? ((const float*)p)[i] : b2f(((const u16*)p)[i]);
}

__device__ __forceinline__ void gload16(const u16* g, u16* l) {
  __builtin_amdgcn_global_load_lds(
      (__attribute__((address_space(1))) void*)(u16*)g,
      (__attribute__((address_space(3))) void*)l, 16, 0, 0);
}

// ---------------- dtype detection ----------------
__global__ void detect_k(const u16* __restrict__ nodes, int* __restrict__ flag) {
  __shared__ int cnt;
  if (threadIdx.x == 0) cnt = 0;
  __syncthreads();
  u16 v = nodes[threadIdx.x];
  int e = (v >> 7) & 0xFF;
  if (e >= 0x48) atomicAdd(&cnt, 1);
  __syncthreads();
  if (threadIdx.x == 0) *flag = (cnt >= 16) ? 1 : 0;
}

__global__ __launch_bounds__(256) void convert_k(const void* __restrict__ src,
                                                 u16* __restrict__ dst, long n,
                                                 const int* __restrict__ flag) {
  long i = (long)blockIdx.x * 256 + threadIdx.x;
  if (i >= n) return;
  if (*flag)
    dst[i] = f2b(((const float*)src)[i]);
  else
    dst[i] = ((const u16*)src)[i];
}

// ---------------- weight prep ----------------
__global__ __launch_bounds__(256) void transpose_k(const u16* __restrict__ in,
                                                   u16* __restrict__ out, int R, int C) {
  __shared__ u16 tile[32][33];
  int c0 = blockIdx.x * 32, r0 = blockIdx.y * 32;
  int tx = threadIdx.x & 31, ty = threadIdx.x >> 5;
  for (int i = 0; i < 32; i += 8) {
    int r = r0 + ty + i, c = c0 + tx;
    if (r < R && c < C) tile[ty + i][tx] = in[(long)r * C + c];
  }
  __syncthreads();
  for (int i = 0; i < 32; i += 8) {
    int r = r0 + tx, c = c0 + ty + i;
    if (r < R && c < C) out[(long)c * R + r] = tile[tx][ty + i];
  }
}

__global__ __launch_bounds__(256) void build_wcat(const u16* __restrict__ W0,
                                                  const u16* __restrict__ W1,
                                                  const u16* __restrict__ W2,
                                                  u16* __restrict__ wcT) {
  int idx = blockIdx.x * 256 + threadIdx.x;
  if (idx >= NS * KCAT) return;
  int w = idx / KCAT, k = idx - w * KCAT;
  const float fan = 36.66060556f;  // sqrt(1344)
  float val;
  if (k < 1024) {
    int u = k >> 5, v = k & 31;
    val = 0.5f * (b2f(W0[(u * 32 + v) * NS + w]) + b2f(W0[(v * 32 + u) * NS + w])) / fan;
  } else if (k < 1280) {
    int j = k - 1024;
    int u = j >> 4, v = j & 15;
    val = 0.5f * (b2f(W1[(u * 16 + v) * NS + w]) + b2f(W1[(v * 16 + u) * NS + w])) /
          (fan * 1.7320508076f);
  } else {
    int j = k - 1280;
    int u = j >> 3, v = j & 7;
    val = 0.5f * (b2f(W2[(u * 8 + v) * NS + w]) + b2f(W2[(v * 8 + u) * NS + w])) /
          (fan * 2.2360679775f);
  }
  wcT[idx] = f2b(val);
}

// ---------------- per-edge geometry + embedding + outer products ----------------
__global__ __launch_bounds__(256) void edge_prep(
    const u16* __restrict__ nodes, const void* __restrict__ pos, const void* __restrict__ cell,
    const void* __restrict__ shift, const int* __restrict__ eidx, const int* __restrict__ batch,
    u16* __restrict__ emb, u16* __restrict__ ocat, int e0, const int* __restrict__ flag) {
  const int wave = threadIdx.x >> 6, lane = threadIdx.x & 63;
  const int el = blockIdx.x * 4 + wave;
  const int e = e0 + el;
  const int f32 = *flag;
  __shared__ u16 sxs[4][FEAT], sxd[4][FEAT];
  const int src = eidx[e], dst = eidx[EE + e];
  for (int i = lane; i < FEAT; i += 64) {
    sxs[wave][i] = nodes[(long)src * FEAT + i];
    sxd[wave][i] = nodes[(long)dst * FEAT + i];
  }
  __syncthreads();
  const int b = batch[src];
  float s0 = rdany(shift, (long)e * 3, f32), s1 = rdany(shift, (long)e * 3 + 1, f32),
        s2 = rdany(shift, (long)e * 3 + 2, f32);
  float d2 = 0.f;
#pragma unroll
  for (int j = 0; j < 3; j++) {
    float tv = s0 * rdany(cell, b * 9 + j, f32) + s1 * rdany(cell, b * 9 + 3 + j, f32) +
               s2 * rdany(cell, b * 9 + 6 + j, f32);
    float rv = rdany(pos, dst * 3 + j, f32) - rdany(pos, src * 3 + j, f32) + tv;
    d2 += rv * rv;
  }
  float dist = sqrtf(d2);
  float r = 1.0f / (dist + 1e-6f);
  const float c0 = 0.5345224838f;   // sqrt(2/7)
  const float pi7 = 0.44879895051f; // pi/7
#pragma unroll
  for (int j = 0; j < 4; j++) {
    int n = lane + 64 * j;
    float val = c0 * sinf((float)(n + 1) * pi7 * r) / r;
    emb[(long)el * NB + n] = f2b(val);
  }
  const u16* xs = sxs[wave];
  const u16* xd = sxd[wave];
  u16* orow = ocat + (long)el * KCAT;
#pragma unroll
  for (int j = 0; j < 16; j++) {
    int k = lane + 64 * j;
    int u = k >> 5, v = k & 31;
    orow[k] = f2b(b2f(xs[u]) * b2f(xd[v]));
  }
#pragma unroll
  for (int j = 0; j < 4; j++) {
    int k = lane + 64 * j;
    int u = k >> 4, v = k & 15;
    float s = 0.f;
#pragma unroll
    for (int i = 0; i < 3; i++) s += b2f(xs[32 + u * 3 + i]) * b2f(xd[32 + v * 3 + i]);
    orow[1024 + k] = f2b(s);
  }
  {
    int u = lane >> 3, v = lane & 7;
    float s = 0.f;
#pragma unroll
    for (int i = 0; i < 5; i++) s += b2f(xs[80 + u * 5 + i]) * b2f(xd[80 + v * 5 + i]);
    orow[1280 + lane] = f2b(s);
  }
}

// ---------------- tiled MFMA GEMM: C(MxN) = act(A(MxK) @ BT(NxK)^T + bias) ----------------
// 1-D grid, XCD-aware swizzle: all N-blocks of one A row-tile land on one XCD.
// HEAD: skip C store; dot silu'd row fragment with hw[col], atomicAdd into outf[row].
template <int ACT, int OF32, int HEAD>
__global__ __launch_bounds__(256) void gemm_bt(const u16* __restrict__ A,
                                               const u16* __restrict__ BT,
                                               const u16* __restrict__ bias,
                                               void* __restrict__ Cv,
                                               const u16* __restrict__ hw,
                                               float* __restrict__ outf, int N, int K) {
  __shared__ __align__(16) u16 lA[128 * 32];
  __shared__ __align__(16) u16 lB[128 * 32];
  const int tid = threadIdx.x;
  const int wave = tid >> 6, lane = tid & 63;
  const int quad = lane >> 4, l16 = lane & 15;

  const int nb_n = N >> 7;
  const int total = gridDim.x;
  const int nb_m = total / nb_n;
  int mi, ni;
  if ((nb_m & 7) == 0) {
    int f = blockIdx.x;
    int xcd = f & 7, s = f >> 3;
    int per = nb_m >> 3;
    mi = xcd * per + s / nb_n;
    ni = s - (s / nb_n) * nb_n;
  } else {
    mi = blockIdx.x / nb_n;
    ni = blockIdx.x - mi * nb_n;
  }
  const long m0 = (long)mi * 128;
  const int n0 = ni * 128;
  const int wm = (wave >> 1) * 64, wn = (wave & 1) * 64;

  f32x4 acc[4][4];
#pragma unroll
  for (int i = 0; i < 4; i++)
#pragma unroll
    for (int j = 0; j < 4; j++) acc[i][j] = (f32x4){0.f, 0.f, 0.f, 0.f};

  const int r0 = tid >> 2, sg = (tid & 3) * 8;
  const u16* Ag0 = A + (m0 + r0) * K + sg;
  const u16* Ag1 = A + (m0 + r0 + 64) * K + sg;
  const u16* Bg0 = BT + (long)(n0 + r0) * K + sg;
  const u16* Bg1 = BT + (long)(n0 + r0 + 64) * K + sg;

  for (int k0 = 0; k0 < K; k0 += 32) {
    gload16(Ag0 + k0, &lA[tid * 8]);
    gload16(Ag1 + k0, &lA[(tid + 256) * 8]);
    gload16(Bg0 + k0, &lB[tid * 8]);
    gload16(Bg1 + k0, &lB[(tid + 256) * 8]);
    __syncthreads();
    bf16x8 af[4], bfr[4];
#pragma unroll
    for (int t = 0; t < 4; t++) {
      af[t] = *(const bf16x8*)&lA[(wm + t * 16 + l16) * 32 + quad * 8];
      bfr[t] = *(const bf16x8*)&lB[(wn + t * 16 + l16) * 32 + quad * 8];
    }
#pragma unroll
    for (int mt = 0; mt < 4; mt++)
#pragma unroll
      for (int nt = 0; nt < 4; nt++)
        acc[mt][nt] =
            __builtin_amdgcn_mfma_f32_16x16x32_bf16(af[mt], bfr[nt], acc[mt][nt], 0, 0, 0);
    __syncthreads();
  }

  float* Cf = (float*)Cv;
  u16* Cb = (u16*)Cv;
  float rsum[4][4];
  if (HEAD) {
#pragma unroll
    for (int mt = 0; mt < 4; mt++)
#pragma unroll
      for (int i = 0; i < 4; i++) rsum[mt][i] = 0.f;
  }
#pragma unroll
  for (int mt = 0; mt < 4; mt++) {
#pragma unroll
    for (int nt = 0; nt < 4; nt++) {
      const int col = n0 + wn + nt * 16 + l16;
      float bv = bias ? b2f(bias[col]) : 0.0f;
      float hwv = HEAD ? b2f(hw[col]) : 0.f;
#pragma unroll
      for (int i = 0; i < 4; i++) {
        long row = m0 + wm + mt * 16 + quad * 4 + i;
        float v = acc[mt][nt][i] + bv;
        if (ACT) v = v / (1.0f + __expf(-v));
        if (HEAD) {
          rsum[mt][i] += v * hwv;
        } else if (OF32) {
          Cf[row * N + col] = v;
        } else {
          Cb[row * N + col] = f2b(v);
        }
      }
    }
  }
  if (HEAD) {
    // reduce across the 16-lane column group (same quad), then one atomic per row
#pragma unroll
    for (int mt = 0; mt < 4; mt++)
#pragma unroll
      for (int i = 0; i < 4; i++) {
        float s = rsum[mt][i];
        s += __shfl_xor(s, 1);
        s += __shfl_xor(s, 2);
        s += __shfl_xor(s, 4);
        s += __shfl_xor(s, 8);
        if (l16 == 0) {
          long row = m0 + wm + mt * 16 + quad * 4 + i;
          atomicAdd(&outf[row], s);
        }
      }
  }
}

// ---------------- LayerNorm * distfilter (in-place over distfilter) ----------------
__global__ __launch_bounds__(256) void ln_mul_k(const float* __restrict__ mixed,
                                                const u16* __restrict__ g,
                                                const u16* __restrict__ bvec,
                                                u16* __restrict__ dfreg) {
  const int wave = threadIdx.x >> 6, lane = threadIdx.x & 63;
  const long e = (long)blockIdx.x * 4 + wave;
  const float* row = mixed + e * NS;
  float x[8];
  f32x4 v0 = *(const f32x4*)&row[lane * 8];
  f32x4 v1 = *(const f32x4*)&row[lane * 8 + 4];
#pragma unroll
  for (int j = 0; j < 4; j++) { x[j] = v0[j]; x[4 + j] = v1[j]; }
  float s = 0.f, sq = 0.f;
#pragma unroll
  for (int j = 0; j < 8; j++) { s += x[j]; sq += x[j] * x[j]; }
  for (int o = 32; o; o >>= 1) { s += __shfl_xor(s, o); sq += __shfl_xor(sq, o); }
  float mu = s * (1.0f / 512.0f);
  float var = sq * (1.0f / 512.0f) - mu * mu;
  float rstd = rsqrtf(var + 1e-5f);
  u16* drow = dfreg + e * NS;
  ushort8 dv = *(const ushort8*)&drow[lane * 8];
  ushort8 ov;
#pragma unroll
  for (int j = 0; j < 8; j++) {
    int c = lane * 8 + j;
    float val = (x[j] - mu) * rstd * b2f(g[c]) + b2f(bvec[c]);
    ov[j] = f2b(val * b2f(dv[j]));
  }
  *(ushort8*)&drow[lane * 8] = ov;
}

// ---------------- final head: bias + dtype convert ----------------
__global__ __launch_bounds__(256) void head_finish(const float* __restrict__ outf,
                                                   const u16* __restrict__ b,
                                                   void* __restrict__ out,
                                                   const int* __restrict__ flag) {
  int e = blockIdx.x * 256 + threadIdx.x;
  float v = outf[e] + b2f(b[0]);
  if (*flag)
    ((float*)out)[e] = v;
  else
    ((u16*)out)[e] = f2b(v);
}

extern "C" void kernel_launch(void* const* d_in, const int* in_sizes, int n_in, void* d_out,
                              int out_size, void* d_ws, size_t ws_size, hipStream_t stream) {
  const int* eidx = (const int*)d_in[19];
  const int* batch = (const int*)d_in[20];

  char* ws = (char*)d_ws;
  size_t off = 0;
  auto alloc = [&](size_t bytes) {
    char* p = ws + off;
    off += (bytes + 255) & ~(size_t)255;
    return p;
  };

  int* flag = (int*)alloc(256);
  float* outf = (float*)alloc((size_t)EE * 4);

  detect_k<<<1, 256, 0, stream>>>((const u16*)d_in[0], flag);

  // normalize all 19 float tensors to bf16 copies
  u16* cv[19];
  for (int i = 0; i < 19; i++) {
    long n = in_sizes[i];
    cv[i] = (u16*)alloc((size_t)n * 2);
    convert_k<<<(int)((n + 255) / 256), 256, 0, stream>>>(d_in[i], cv[i], n, flag);
  }
  const u16* nodes = cv[0];
  const u16* W0 = cv[4];
  const u16* W1 = cv[5];
  const u16* W2 = cv[6];
  const u16* ln_g = cv[7];
  const u16* ln_b = cv[8];
  const u16* df_w1 = cv[9];
  const u16* df_b1 = cv[10];
  const u16* df_w2 = cv[11];
  const u16* df_b2 = cv[12];
  const u16* mi_w1 = cv[13];
  const u16* mi_b1 = cv[14];
  const u16* mi_w2 = cv[15];
  const u16* mi_b2 = cv[16];
  const u16* mo_w = cv[17];
  const u16* mo_b = cv[18];

  u16* w1T = (u16*)alloc(1024 * 256 * 2);
  u16* w2T = (u16*)alloc(512 * 1024 * 2);
  u16* m1T = (u16*)alloc(1024 * 512 * 2);
  u16* m2T = (u16*)alloc((size_t)1024 * 1024 * 2);
  u16* wcT = (u16*)alloc((size_t)NS * KCAT * 2);

  // per-edge bytes: ocat 2688 + emb 512 + h1/mixed 2048 + dfb 1024 = 6272
  int nchunk = 1;
  while (nchunk < 64) {
    size_t CHs = (size_t)(EE / nchunk);
    size_t need = off + CHs * 6272 + 8192;
    if (need <= ws_size) break;
    nchunk <<= 1;
  }
  const int CH = EE / nchunk;

  u16* ocat = (u16*)alloc((size_t)CH * KCAT * 2);  // reused as h2
  u16* emb = (u16*)alloc((size_t)CH * NB * 2);
  u16* h1 = (u16*)alloc((size_t)CH * 1024 * 2);  // reused as mixed(f32)
  u16* dfb = (u16*)alloc((size_t)CH * NS * 2);   // distfilter, then reg in-place
  u16* h2 = ocat;
  float* mixed = (float*)h1;

  // weight prep (once)
  transpose_k<<<dim3(1024 / 32, 256 / 32), 256, 0, stream>>>(df_w1, w1T, 256, 1024);
  transpose_k<<<dim3(512 / 32, 1024 / 32), 256, 0, stream>>>(df_w2, w2T, 1024, 512);
  transpose_k<<<dim3(1024 / 32, 512 / 32), 256, 0, stream>>>(mi_w1, m1T, 512, 1024);
  transpose_k<<<dim3(1024 / 32, 1024 / 32), 256, 0, stream>>>(mi_w2, m2T, 1024, 1024);
  build_wcat<<<(NS * KCAT + 255) / 256, 256, 0, stream>>>(W0, W1, W2, wcT);

  hipMemsetAsync(outf, 0, (size_t)EE * 4, stream);

  const int RB = CH / 128;  // m-row blocks per chunk
  for (int c = 0; c < nchunk; c++) {
    const int eb = c * CH;
    edge_prep<<<CH / 4, 256, 0, stream>>>(nodes, d_in[1], d_in[2], d_in[3], eidx, batch, emb,
                                          ocat, eb, flag);

    // distance-filter MLP
    gemm_bt<1, 0, 0><<<RB * 8, 256, 0, stream>>>(emb, w1T, df_b1, h1, nullptr, nullptr, 1024, 256);
    gemm_bt<0, 0, 0><<<RB * 4, 256, 0, stream>>>(h1, w2T, df_b2, dfb, nullptr, nullptr, 512, 1024);

    // tensor-product mixing -> mixed (fp32)
    gemm_bt<0, 1, 0><<<RB * 4, 256, 0, stream>>>(ocat, wcT, nullptr, mixed, nullptr, nullptr, 512,
                                                 1344);

    // LayerNorm * distfilter -> reg (in-place over dfb)
    ln_mul_k<<<CH / 4, 256, 0, stream>>>(mixed, ln_g, ln_b, dfb);

    // output MLP; last GEMM fuses the head dot-product
    gemm_bt<1, 0, 0><<<RB * 8, 256, 0, stream>>>(dfb, m1T, mi_b1, h2, nullptr, nullptr, 1024, 512);
    gemm_bt<1, 0, 1><<<RB * 8, 256, 0, stream>>>(h2, m2T, mi_b2, nullptr, mo_w, outf + eb, 1024,
                                                 1024);
  }
  head_finish<<<EE / 256, 256, 0, stream>>>(outf, mo_b, d_out, flag);
}

// Round 5
// 1621.025 us; speedup vs baseline: 1.2049x; 1.0867x over previous
//
#include <hip/hip_runtime.h>

#define EE 131072
#define NNODE 16384
#define FEAT 120
#define NS 512
#define NB 256
#define KCAT 1344

typedef unsigned short u16;
typedef __bf16 bf16x8 __attribute__((ext_vector_type(8)));
typedef float f32x4 __attribute__((ext_vector_type(4)));
typedef float f32x16 __attribute__((ext_vector_type(16)));
typedef unsigned short ushort8 __attribute__((ext_vector_type(8)));

__device__ __forceinline__ float b2f(u16 u) {
  union { unsigned int i; float f; } x; x.i = ((unsigned int)u) << 16; return x.f;
}
__device__ __forceinline__ u16 f2b(float f) {
  union { float f; unsigned int i; } x; x.f = f;
  unsigned int lsb = (x.i >> 16) & 1u;
  x.i += 0x7fffu + lsb;
  return (u16)(x.i >> 16);
}
__device__ __forceinline__ u16 f2b_fast(float f) {
  __bf16 h = (__bf16)f;
  union { __bf16 h; u16 u; } x; x.h = h; return x.u;
}
__device__ __forceinline__ float rdany(const void* p, long i, int f32) {
  return f32 ? ((const float*)p)[i] : b2f(((const u16*)p)[i]);
}

__device__ __forceinline__ void gload16(const u16* g, u16* l) {
  __builtin_amdgcn_global_load_lds(
      (__attribute__((address_space(1))) void*)(u16*)g,
      (__attribute__((address_space(3))) void*)l, 16, 0, 0);
}

// ---------------- dtype detection ----------------
__global__ void detect_k(const u16* __restrict__ nodes, int* __restrict__ flag) {
  __shared__ int cnt;
  if (threadIdx.x == 0) cnt = 0;
  __syncthreads();
  u16 v = nodes[threadIdx.x];
  int e = (v >> 7) & 0xFF;
  if (e >= 0x48) atomicAdd(&cnt, 1);
  __syncthreads();
  if (threadIdx.x == 0) *flag = (cnt >= 16) ? 1 : 0;
}

__global__ __launch_bounds__(256) void convert_k(const void* __restrict__ src,
                                                 u16* __restrict__ dst, long n,
                                                 const int* __restrict__ flag) {
  long i = (long)blockIdx.x * 256 + threadIdx.x;
  if (i >= n) return;
  if (*flag)
    dst[i] = f2b(((const float*)src)[i]);
  else
    dst[i] = ((const u16*)src)[i];
}

// ---------------- weight prep ----------------
__global__ __launch_bounds__(256) void transpose_k(const u16* __restrict__ in,
                                                   u16* __restrict__ out, int R, int C) {
  __shared__ u16 tile[32][33];
  int c0 = blockIdx.x * 32, r0 = blockIdx.y * 32;
  int tx = threadIdx.x & 31, ty = threadIdx.x >> 5;
  for (int i = 0; i < 32; i += 8) {
    int r = r0 + ty + i, c = c0 + tx;
    if (r < R && c < C) tile[ty + i][tx] = in[(long)r * C + c];
  }
  __syncthreads();
  for (int i = 0; i < 32; i += 8) {
    int r = r0 + tx, c = c0 + ty + i;
    if (r < R && c < C) out[(long)c * R + r] = tile[tx][ty + i];
  }
}

__global__ __launch_bounds__(256) void build_wcat(const u16* __restrict__ W0,
                                                  const u16* __restrict__ W1,
                                                  const u16* __restrict__ W2,
                                                  u16* __restrict__ wcT) {
  int idx = blockIdx.x * 256 + threadIdx.x;
  if (idx >= NS * KCAT) return;
  int w = idx / KCAT, k = idx - w * KCAT;
  const float fan = 36.66060556f;  // sqrt(1344)
  float val;
  if (k < 1024) {
    int u = k >> 5, v = k & 31;
    val = 0.5f * (b2f(W0[(u * 32 + v) * NS + w]) + b2f(W0[(v * 32 + u) * NS + w])) / fan;
  } else if (k < 1280) {
    int j = k - 1024;
    int u = j >> 4, v = j & 15;
    val = 0.5f * (b2f(W1[(u * 16 + v) * NS + w]) + b2f(W1[(v * 16 + u) * NS + w])) /
          (fan * 1.7320508076f);
  } else {
    int j = k - 1280;
    int u = j >> 3, v = j & 7;
    val = 0.5f * (b2f(W2[(u * 8 + v) * NS + w]) + b2f(W2[(v * 8 + u) * NS + w])) /
          (fan * 2.2360679775f);
  }
  wcT[idx] = f2b(val);
}

// ---------------- per-edge geometry + embedding + outer products ----------------
__global__ __launch_bounds__(256) void edge_prep(
    const u16* __restrict__ nodes, const void* __restrict__ pos, const void* __restrict__ cell,
    const void* __restrict__ shift, const int* __restrict__ eidx, const int* __restrict__ batch,
    u16* __restrict__ emb, u16* __restrict__ ocat, int e0, const int* __restrict__ flag) {
  const int wave = threadIdx.x >> 6, lane = threadIdx.x & 63;
  const int el = blockIdx.x * 4 + wave;
  const int e = e0 + el;
  const int f32 = *flag;
  __shared__ u16 sxs[4][FEAT], sxd[4][FEAT];
  const int src = eidx[e], dst = eidx[EE + e];
  for (int i = lane; i < FEAT; i += 64) {
    sxs[wave][i] = nodes[(long)src * FEAT + i];
    sxd[wave][i] = nodes[(long)dst * FEAT + i];
  }
  __syncthreads();
  const int b = batch[src];
  float s0 = rdany(shift, (long)e * 3, f32), s1 = rdany(shift, (long)e * 3 + 1, f32),
        s2 = rdany(shift, (long)e * 3 + 2, f32);
  float d2 = 0.f;
#pragma unroll
  for (int j = 0; j < 3; j++) {
    float tv = s0 * rdany(cell, b * 9 + j, f32) + s1 * rdany(cell, b * 9 + 3 + j, f32) +
               s2 * rdany(cell, b * 9 + 6 + j, f32);
    float rv = rdany(pos, dst * 3 + j, f32) - rdany(pos, src * 3 + j, f32) + tv;
    d2 += rv * rv;
  }
  float dist = sqrtf(d2);
  float r = 1.0f / (dist + 1e-6f);
  const float c0 = 0.5345224838f;   // sqrt(2/7)
  const float pi7 = 0.44879895051f; // pi/7
#pragma unroll
  for (int j = 0; j < 4; j++) {
    int n = lane + 64 * j;
    float val = c0 * sinf((float)(n + 1) * pi7 * r) / r;
    emb[(long)el * NB + n] = f2b(val);
  }
  const u16* xs = sxs[wave];
  const u16* xd = sxd[wave];
  u16* orow = ocat + (long)el * KCAT;
#pragma unroll
  for (int j = 0; j < 16; j++) {
    int k = lane + 64 * j;
    int u = k >> 5, v = k & 31;
    orow[k] = f2b(b2f(xs[u]) * b2f(xd[v]));
  }
#pragma unroll
  for (int j = 0; j < 4; j++) {
    int k = lane + 64 * j;
    int u = k >> 4, v = k & 15;
    float s = 0.f;
#pragma unroll
    for (int i = 0; i < 3; i++) s += b2f(xs[32 + u * 3 + i]) * b2f(xd[32 + v * 3 + i]);
    orow[1024 + k] = f2b(s);
  }
  {
    int u = lane >> 3, v = lane & 7;
    float s = 0.f;
#pragma unroll
    for (int i = 0; i < 5; i++) s += b2f(xs[80 + u * 5 + i]) * b2f(xd[80 + v * 5 + i]);
    orow[1280 + lane] = f2b(s);
  }
}

// ---------------- tiled MFMA GEMM: C(MxN) = act(A(MxK) @ BT(NxK)^T + bias) ----------------
// 128x128 tile, BK=64, 32x32x16 MFMA, XCD swizzle, XOR-swizzled LDS columns.
// LDS[r][slot] = G[r][slot ^ (r&7)] (8-elem segments); read side un-permutes.
template <int ACT, int OF32, int HEAD>
__global__ __launch_bounds__(256) void gemm_bt(const u16* __restrict__ A,
                                               const u16* __restrict__ BT,
                                               const u16* __restrict__ bias,
                                               void* __restrict__ Cv,
                                               const u16* __restrict__ hw,
                                               float* __restrict__ outf, int N, int K) {
  __shared__ __align__(16) u16 lA[128 * 64];
  __shared__ __align__(16) u16 lB[128 * 64];
  const int tid = threadIdx.x;
  const int wave = tid >> 6, lane = tid & 63;
  const int half = lane >> 5, l32 = lane & 31, r7 = lane & 7;

  const int nb_n = N >> 7;
  const int nb_m = gridDim.x / nb_n;
  int mi, ni;
  if ((nb_m & 7) == 0) {
    int f = blockIdx.x;
    int xcd = f & 7, s = f >> 3;
    int per = nb_m >> 3;
    mi = xcd * per + s / nb_n;
    ni = s - (s / nb_n) * nb_n;
  } else {
    mi = blockIdx.x / nb_n;
    ni = blockIdx.x - mi * nb_n;
  }
  const long m0 = (long)mi * 128;
  const int n0 = ni * 128;
  const int wm = (wave >> 1) * 64, wn = (wave & 1) * 64;

  f32x16 acc[2][2];
#pragma unroll
  for (int i = 0; i < 2; i++)
#pragma unroll
    for (int j = 0; j < 2; j++)
#pragma unroll
      for (int q = 0; q < 16; q++) acc[i][j][q] = 0.f;

  // staging: thread stages rows {srow + 32*ro}, 8-elem segment gseg (XOR-permuted)
  const int srow = tid >> 3;
  const int gseg = (tid & 7) ^ (srow & 7);
  const u16* Ag = A + (m0 + srow) * K + gseg * 8;
  const u16* Bg = BT + (long)(n0 + srow) * K + gseg * 8;
  u16* la = &lA[tid * 8];
  u16* lb = &lB[tid * 8];

  for (int k0 = 0; k0 < K; k0 += 64) {
#pragma unroll
    for (int ro = 0; ro < 4; ro++) gload16(Ag + (long)(ro * 32) * K + k0, la + ro * 2048);
#pragma unroll
    for (int ro = 0; ro < 4; ro++) gload16(Bg + (long)(ro * 32) * K + k0, lb + ro * 2048);
    __syncthreads();
#pragma unroll
    for (int s = 0; s < 4; s++) {
      const int sl = ((((s << 1) + half) ^ r7) << 3);
      bf16x8 a0 = *(const bf16x8*)&lA[(wm + l32) * 64 + sl];
      bf16x8 a1 = *(const bf16x8*)&lA[(wm + 32 + l32) * 64 + sl];
      bf16x8 b0 = *(const bf16x8*)&lB[(wn + l32) * 64 + sl];
      bf16x8 b1 = *(const bf16x8*)&lB[(wn + 32 + l32) * 64 + sl];
      acc[0][0] = __builtin_amdgcn_mfma_f32_32x32x16_bf16(a0, b0, acc[0][0], 0, 0, 0);
      acc[0][1] = __builtin_amdgcn_mfma_f32_32x32x16_bf16(a0, b1, acc[0][1], 0, 0, 0);
      acc[1][0] = __builtin_amdgcn_mfma_f32_32x32x16_bf16(a1, b0, acc[1][0], 0, 0, 0);
      acc[1][1] = __builtin_amdgcn_mfma_f32_32x32x16_bf16(a1, b1, acc[1][1], 0, 0, 0);
    }
    __syncthreads();
  }

  float* Cf = (float*)Cv;
  u16* Cb = (u16*)Cv;
  float rsum[2][16];
  if (HEAD) {
#pragma unroll
    for (int mt = 0; mt < 2; mt++)
#pragma unroll
      for (int rg = 0; rg < 16; rg++) rsum[mt][rg] = 0.f;
  }
#pragma unroll
  for (int mt = 0; mt < 2; mt++) {
#pragma unroll
    for (int nt = 0; nt < 2; nt++) {
      const int col = n0 + wn + nt * 32 + l32;
      float bv = bias ? b2f(bias[col]) : 0.0f;
      float hwv = HEAD ? b2f(hw[col]) : 0.f;
#pragma unroll
      for (int rg = 0; rg < 16; rg++) {
        long row = m0 + wm + mt * 32 + (rg & 3) + ((rg >> 2) << 3) + (half << 2);
        float v = acc[mt][nt][rg] + bv;
        if (ACT) v = __fdividef(v, 1.0f + __expf(-v));
        if (HEAD) {
          rsum[mt][rg] += v * hwv;
        } else if (OF32) {
          Cf[row * N + col] = v;
        } else {
          Cb[row * N + col] = f2b_fast(v);
        }
      }
    }
  }
  if (HEAD) {
#pragma unroll
    for (int mt = 0; mt < 2; mt++)
#pragma unroll
      for (int rg = 0; rg < 16; rg++) {
        float s = rsum[mt][rg];
        s += __shfl_xor(s, 1);
        s += __shfl_xor(s, 2);
        s += __shfl_xor(s, 4);
        s += __shfl_xor(s, 8);
        s += __shfl_xor(s, 16);
        if (l32 == 0) {
          long row = m0 + wm + mt * 32 + (rg & 3) + ((rg >> 2) << 3) + (half << 2);
          atomicAdd(&outf[row], s);
        }
      }
  }
}

// ---------------- LayerNorm * distfilter (in-place over distfilter) ----------------
__global__ __launch_bounds__(256) void ln_mul_k(const float* __restrict__ mixed,
                                                const u16* __restrict__ g,
                                                const u16* __restrict__ bvec,
                                                u16* __restrict__ dfreg) {
  const int wave = threadIdx.x >> 6, lane = threadIdx.x & 63;
  const long e = (long)blockIdx.x * 4 + wave;
  const float* row = mixed + e * NS;
  float x[8];
  f32x4 v0 = *(const f32x4*)&row[lane * 8];
  f32x4 v1 = *(const f32x4*)&row[lane * 8 + 4];
#pragma unroll
  for (int j = 0; j < 4; j++) { x[j] = v0[j]; x[4 + j] = v1[j]; }
  float s = 0.f, sq = 0.f;
#pragma unroll
  for (int j = 0; j < 8; j++) { s += x[j]; sq += x[j] * x[j]; }
  for (int o = 32; o; o >>= 1) { s += __shfl_xor(s, o); sq += __shfl_xor(sq, o); }
  float mu = s * (1.0f / 512.0f);
  float var = sq * (1.0f / 512.0f) - mu * mu;
  float rstd = rsqrtf(var + 1e-5f);
  u16* drow = dfreg + e * NS;
  ushort8 dv = *(const ushort8*)&drow[lane * 8];
  ushort8 ov;
#pragma unroll
  for (int j = 0; j < 8; j++) {
    int c = lane * 8 + j;
    float val = (x[j] - mu) * rstd * b2f(g[c]) + b2f(bvec[c]);
    ov[j] = f2b(val * b2f(dv[j]));
  }
  *(ushort8*)&drow[lane * 8] = ov;
}

// ---------------- final head: bias + dtype convert ----------------
__global__ __launch_bounds__(256) void head_finish(const float* __restrict__ outf,
                                                   const u16* __restrict__ b,
                                                   void* __restrict__ out,
                                                   const int* __restrict__ flag) {
  int e = blockIdx.x * 256 + threadIdx.x;
  float v = outf[e] + b2f(b[0]);
  if (*flag)
    ((float*)out)[e] = v;
  else
    ((u16*)out)[e] = f2b(v);
}

extern "C" void kernel_launch(void* const* d_in, const int* in_sizes, int n_in, void* d_out,
                              int out_size, void* d_ws, size_t ws_size, hipStream_t stream) {
  const int* eidx = (const int*)d_in[19];
  const int* batch = (const int*)d_in[20];

  char* ws = (char*)d_ws;
  size_t off = 0;
  auto alloc = [&](size_t bytes) {
    char* p = ws + off;
    off += (bytes + 255) & ~(size_t)255;
    return p;
  };

  int* flag = (int*)alloc(256);
  float* outf = (float*)alloc((size_t)EE * 4);

  detect_k<<<1, 256, 0, stream>>>((const u16*)d_in[0], flag);

  // normalize all 19 float tensors to bf16 copies
  u16* cv[19];
  for (int i = 0; i < 19; i++) {
    long n = in_sizes[i];
    cv[i] = (u16*)alloc((size_t)n * 2);
    convert_k<<<(int)((n + 255) / 256), 256, 0, stream>>>(d_in[i], cv[i], n, flag);
  }
  const u16* nodes = cv[0];
  const u16* W0 = cv[4];
  const u16* W1 = cv[5];
  const u16* W2 = cv[6];
  const u16* ln_g = cv[7];
  const u16* ln_b = cv[8];
  const u16* df_w1 = cv[9];
  const u16* df_b1 = cv[10];
  const u16* df_w2 = cv[11];
  const u16* df_b2 = cv[12];
  const u16* mi_w1 = cv[13];
  const u16* mi_b1 = cv[14];
  const u16* mi_w2 = cv[15];
  const u16* mi_b2 = cv[16];
  const u16* mo_w = cv[17];
  const u16* mo_b = cv[18];

  u16* w1T = (u16*)alloc(1024 * 256 * 2);
  u16* w2T = (u16*)alloc(512 * 1024 * 2);
  u16* m1T = (u16*)alloc(1024 * 512 * 2);
  u16* m2T = (u16*)alloc((size_t)1024 * 1024 * 2);
  u16* wcT = (u16*)alloc((size_t)NS * KCAT * 2);

  // per-edge bytes: ocat 2688 + emb 512 + h1/mixed 2048 + dfb 1024 = 6272
  int nchunk = 1;
  while (nchunk < 64) {
    size_t CHs = (size_t)(EE / nchunk);
    size_t need = off + CHs * 6272 + 8192;
    if (need <= ws_size) break;
    nchunk <<= 1;
  }
  const int CH = EE / nchunk;

  u16* ocat = (u16*)alloc((size_t)CH * KCAT * 2);  // reused as h2
  u16* emb = (u16*)alloc((size_t)CH * NB * 2);
  u16* h1 = (u16*)alloc((size_t)CH * 1024 * 2);  // reused as mixed(f32)
  u16* dfb = (u16*)alloc((size_t)CH * NS * 2);   // distfilter, then reg in-place
  u16* h2 = ocat;
  float* mixed = (float*)h1;

  // weight prep (once)
  transpose_k<<<dim3(1024 / 32, 256 / 32), 256, 0, stream>>>(df_w1, w1T, 256, 1024);
  transpose_k<<<dim3(512 / 32, 1024 / 32), 256, 0, stream>>>(df_w2, w2T, 1024, 512);
  transpose_k<<<dim3(1024 / 32, 512 / 32), 256, 0, stream>>>(mi_w1, m1T, 512, 1024);
  transpose_k<<<dim3(1024 / 32, 1024 / 32), 256, 0, stream>>>(mi_w2, m2T, 1024, 1024);
  build_wcat<<<(NS * KCAT + 255) / 256, 256, 0, stream>>>(W0, W1, W2, wcT);

  hipMemsetAsync(outf, 0, (size_t)EE * 4, stream);

  const int RB = CH / 128;  // m-row blocks per chunk
  for (int c = 0; c < nchunk; c++) {
    const int eb = c * CH;
    edge_prep<<<CH / 4, 256, 0, stream>>>(nodes, d_in[1], d_in[2], d_in[3], eidx, batch, emb,
                                          ocat, eb, flag);

    // distance-filter MLP
    gemm_bt<1, 0, 0><<<RB * 8, 256, 0, stream>>>(emb, w1T, df_b1, h1, nullptr, nullptr, 1024, 256);
    gemm_bt<0, 0, 0><<<RB * 4, 256, 0, stream>>>(h1, w2T, df_b2, dfb, nullptr, nullptr, 512, 1024);

    // tensor-product mixing -> mixed (fp32)
    gemm_bt<0, 1, 0><<<RB * 4, 256, 0, stream>>>(ocat, wcT, nullptr, mixed, nullptr, nullptr, 512,
                                                 1344);

    // LayerNorm * distfilter -> reg (in-place over dfb)
    ln_mul_k<<<CH / 4, 256, 0, stream>>>(mixed, ln_g, ln_b, dfb);

    // output MLP; last GEMM fuses the head dot-product
    gemm_bt<1, 0, 0><<<RB * 8, 256, 0, stream>>>(dfb, m1T, mi_b1, h2, nullptr, nullptr, 1024, 512);
    gemm_bt<1, 0, 1><<<RB * 8, 256, 0, stream>>>(h2, m2T, mi_b2, nullptr, mo_w, outf + eb, 1024,
                                                 1024);
  }
  head_finish<<<EE / 256, 256, 0, stream>>>(outf, mo_b, d_out, flag);
}